// Round 1
// baseline (1589.737 us; speedup 1.0000x reference)
//
#include <hip/hip_runtime.h>
#include <hip/hip_bf16.h>
#include <math.h>

// GAT 3-layer forward, MI355X. Round 0: fp32 everywhere, correctness-first.
// Workspace usage ~218 MB: bufA/bufB (N*512 f32 each) + per-edge alpha + CSR.

__device__ __forceinline__ float leaky02(float x){ return x > 0.f ? x : 0.2f*x; }

// ---------------- CSR build over dst ----------------
__global__ void count_kernel(const int* __restrict__ dst, int* __restrict__ cnt, int E){
  int e = blockIdx.x*blockDim.x + threadIdx.x;
  if (e < E) atomicAdd(&cnt[dst[e]], 1);
}

__global__ __launch_bounds__(1024) void scan_kernel(const int* __restrict__ cnt, int* __restrict__ row_ptr, int N){
  __shared__ int sd[1024];
  __shared__ int carry;
  if (threadIdx.x==0) carry = 0;
  __syncthreads();
  for (int base=0; base<N; base+=1024){
    int i = base + threadIdx.x;
    int v = (i<N) ? cnt[i] : 0;
    sd[threadIdx.x] = v;
    __syncthreads();
    for (int off=1; off<1024; off<<=1){
      int t = (threadIdx.x >= off) ? sd[threadIdx.x-off] : 0;
      __syncthreads();
      sd[threadIdx.x] += t;
      __syncthreads();
    }
    int incl = sd[threadIdx.x] + carry;
    if (i < N) row_ptr[i+1] = incl;
    __syncthreads();
    if (threadIdx.x == 1023) carry = incl;
    __syncthreads();
  }
  if (threadIdx.x == 0) row_ptr[0] = 0;
}

__global__ void scatter_kernel(const int* __restrict__ dst, const int* __restrict__ row_ptr,
                               int* __restrict__ cursor, int* __restrict__ csr, int E){
  int e = blockIdx.x*blockDim.x + threadIdx.x;
  if (e < E){
    int d = dst[e];
    int pos = row_ptr[d] + atomicAdd(&cursor[d], 1);
    csr[pos] = e;
  }
}

// ---------------- fold We with a_e:  wf[d][l*8+h] = sum_c We_l[h*C+c][d]*ae_l[h][c] ----------------
__global__ void wfold_kernel(const float* __restrict__ We0, const float* __restrict__ ae0,
                             const float* __restrict__ We1, const float* __restrict__ ae1,
                             const float* __restrict__ We2, const float* __restrict__ ae2,
                             float* __restrict__ wf){
  int t = blockIdx.x*blockDim.x + threadIdx.x;
  if (t >= 147*24) return;
  int d = t / 24, j = t % 24;
  int l = j >> 3, h = j & 7;
  const float* We = (l==0) ? We0 : (l==1) ? We1 : We2;
  const float* ae = (l==0) ? ae0 : (l==1) ? ae1 : ae2;
  int C = (l==2) ? 32 : 64;
  float s = 0.f;
  for (int c=0;c<C;c++) s = fmaf(We[(size_t)(h*C+c)*147 + d], ae[h*C+c], s);
  wf[t] = s;
}

// ---------------- per-edge attention-logit edge term: alphaE[e][h] = ea[e] . wf[:, l*8+h] ----------------
__global__ __launch_bounds__(256) void edge_alpha_kernel(const float* __restrict__ ea, const float* __restrict__ wf,
                                                         int l, float* __restrict__ alphaE, int E){
  __shared__ float wfl[147*8];
  for (int i=threadIdx.x; i<147*8; i+=256) wfl[i] = wf[(i>>3)*24 + l*8 + (i&7)];
  __syncthreads();
  int e = blockIdx.x*256 + threadIdx.x;
  if (e >= E) return;
  const float* row = ea + (size_t)e*147;
  float acc[8] = {0,0,0,0,0,0,0,0};
  for (int d=0; d<147; d++){
    float v = row[d];
    #pragma unroll
    for (int h=0;h<8;h++) acc[h] = fmaf(v, wfl[d*8+h], acc[h]);
  }
  #pragma unroll
  for (int h=0;h<8;h++) alphaE[(size_t)e*8 + h] = acc[h];
}

// ---------------- self-loop edge term: mean of incoming alphaE (linear in ea => equals loop_attr . w_e) ----------------
__global__ void loop_alpha_kernel(const float* __restrict__ alphaE, const int* __restrict__ row_ptr,
                                  const int* __restrict__ csr, float* __restrict__ loopAE, int N){
  int t = blockIdx.x*blockDim.x + threadIdx.x;
  int n = t >> 3;
  if (n >= N) return;
  int h = t & 7;
  int row = row_ptr[n], end = row_ptr[n+1];
  float s = 0.f;
  for (int i=row;i<end;i++) s += alphaE[(size_t)csr[i]*8 + h];
  loopAE[t] = s / fmaxf((float)(end-row), 1.0f);
}

// ---------------- per-node alpha_s, alpha_d from xp ----------------
template<int HC>
__global__ void alpha_sd_kernel(const float* __restrict__ xp, const float* __restrict__ a_s, const float* __restrict__ a_d,
                                float* __restrict__ alphaS, float* __restrict__ alphaD, int N){
  constexpr int C = HC/8;
  int t = blockIdx.x*blockDim.x + threadIdx.x;
  int n = t >> 3;
  if (n >= N) return;
  int h = t & 7;
  const float* xr = xp + (size_t)n*HC + h*C;
  const float* sr = a_s + h*C;
  const float* dr = a_d + h*C;
  float ss = 0.f, sd = 0.f;
  for (int c=0;c<C;c++){ float v = xr[c]; ss = fmaf(v, sr[c], ss); sd = fmaf(v, dr[c], sd); }
  alphaS[t] = ss; alphaD[t] = sd;
}

// ---------------- fp32 GEMM: C[M][Nn] = A[M][K] * B[Nn][K]^T  (both K-contiguous) ----------------
__global__ __launch_bounds__(256) void gemm_nt_kernel(const float* __restrict__ A, const float* __restrict__ B,
                                                      float* __restrict__ C, int M, int Nn, int K){
  __shared__ float As[32][68];   // K-major, padded row 68 floats (16B-aligned rows)
  __shared__ float Bs[32][68];
  int m0 = blockIdx.x * 64;
  int n0 = blockIdx.y * 64;
  int tx = threadIdx.x & 15, ty = threadIdx.x >> 4;
  float acc[4][4] = {};
  for (int k0=0; k0<K; k0+=32){
    #pragma unroll
    for (int q=0;q<2;q++){
      int idx = threadIdx.x + q*256;       // 512 float4 slots = 64 rows x 8
      int r = idx >> 3, cg = idx & 7;
      int gr = m0 + r;
      float4 v = make_float4(0.f,0.f,0.f,0.f);
      if (gr < M) v = *reinterpret_cast<const float4*>(A + (size_t)gr*K + k0 + cg*4);
      As[cg*4+0][r]=v.x; As[cg*4+1][r]=v.y; As[cg*4+2][r]=v.z; As[cg*4+3][r]=v.w;
    }
    #pragma unroll
    for (int q=0;q<2;q++){
      int idx = threadIdx.x + q*256;
      int r = idx >> 3, cg = idx & 7;
      float4 v = *reinterpret_cast<const float4*>(B + (size_t)(n0 + r)*K + k0 + cg*4);
      Bs[cg*4+0][r]=v.x; Bs[cg*4+1][r]=v.y; Bs[cg*4+2][r]=v.z; Bs[cg*4+3][r]=v.w;
    }
    __syncthreads();
    #pragma unroll
    for (int k=0;k<32;k++){
      float4 a4 = *reinterpret_cast<const float4*>(&As[k][ty*4]);
      float4 b4 = *reinterpret_cast<const float4*>(&Bs[k][tx*4]);
      float a[4] = {a4.x,a4.y,a4.z,a4.w};
      float b[4] = {b4.x,b4.y,b4.z,b4.w};
      #pragma unroll
      for (int r=0;r<4;r++)
        #pragma unroll
        for (int c=0;c<4;c++) acc[r][c] = fmaf(a[r], b[c], acc[r][c]);
    }
    __syncthreads();
  }
  #pragma unroll
  for (int r=0;r<4;r++){
    int gr = m0 + ty*4 + r;
    if (gr < M){
      float4 v = make_float4(acc[r][0],acc[r][1],acc[r][2],acc[r][3]);
      *reinterpret_cast<float4*>(C + (size_t)gr*Nn + n0 + tx*4) = v;
    }
  }
}

// ---------------- fused per-dst softmax + weighted aggregate (one wave per node) ----------------
template<int HC>
__global__ __launch_bounds__(256) void aggregate_kernel(
    const float* __restrict__ xp, const float* __restrict__ alphaS, const float* __restrict__ alphaD,
    const float* __restrict__ alphaE, const float* __restrict__ loopAE,
    const int* __restrict__ row_ptr, const int* __restrict__ csr, const int* __restrict__ src,
    const float* __restrict__ bias, float* __restrict__ out, int N, int apply_elu){
  constexpr int KR = HC/64;
  int n = blockIdx.x*(blockDim.x>>6) + (threadIdx.x>>6);
  int lane = threadIdx.x & 63;
  if (n >= N) return;
  int row = row_ptr[n], end = row_ptr[n+1];
  float adn[8], ls[8], mx[8];
  {
    float4 a0 = *reinterpret_cast<const float4*>(alphaS + (size_t)n*8);
    float4 a1 = *reinterpret_cast<const float4*>(alphaS + (size_t)n*8 + 4);
    float4 d0 = *reinterpret_cast<const float4*>(alphaD + (size_t)n*8);
    float4 d1 = *reinterpret_cast<const float4*>(alphaD + (size_t)n*8 + 4);
    float4 l0 = *reinterpret_cast<const float4*>(loopAE + (size_t)n*8);
    float4 l1 = *reinterpret_cast<const float4*>(loopAE + (size_t)n*8 + 4);
    float asn[8] = {a0.x,a0.y,a0.z,a0.w,a1.x,a1.y,a1.z,a1.w};
    float tdn[8] = {d0.x,d0.y,d0.z,d0.w,d1.x,d1.y,d1.z,d1.w};
    float la [8] = {l0.x,l0.y,l0.z,l0.w,l1.x,l1.y,l1.z,l1.w};
    #pragma unroll
    for (int h=0;h<8;h++){ adn[h]=tdn[h]; ls[h] = leaky02(asn[h]+adn[h]+la[h]); mx[h]=ls[h]; }
  }
  // pass 1: per-head running max over incoming edges (+ self-loop already in mx)
  for (int i=row;i<end;i++){
    int e = csr[i]; int s = src[e];
    float4 s0 = *reinterpret_cast<const float4*>(alphaS + (size_t)s*8);
    float4 s1 = *reinterpret_cast<const float4*>(alphaS + (size_t)s*8 + 4);
    float4 e0 = *reinterpret_cast<const float4*>(alphaE + (size_t)e*8);
    float4 e1 = *reinterpret_cast<const float4*>(alphaE + (size_t)e*8 + 4);
    float sv[8] = {s0.x,s0.y,s0.z,s0.w,s1.x,s1.y,s1.z,s1.w};
    float ev[8] = {e0.x,e0.y,e0.z,e0.w,e1.x,e1.y,e1.z,e1.w};
    #pragma unroll
    for (int h=0;h<8;h++){ float t = leaky02(sv[h]+adn[h]+ev[h]); mx[h]=fmaxf(mx[h],t); }
  }
  float denom[8], exs[8], acc[KR];
  #pragma unroll
  for (int h=0;h<8;h++){ exs[h] = __expf(ls[h]-mx[h]); denom[h]=exs[h]; }
  const float* xn = xp + (size_t)n*HC;
  #pragma unroll
  for (int k=0;k<KR;k++){
    float exk = (HC==512) ? exs[k] : ((lane & 32) ? exs[2*k+1] : exs[2*k]);
    acc[k] = exk * xn[lane + 64*k];
  }
  // pass 2: unnormalized exp-weighted gather-accumulate + denom
  for (int i=row;i<end;i++){
    int e = csr[i]; int s = src[e];
    float4 s0 = *reinterpret_cast<const float4*>(alphaS + (size_t)s*8);
    float4 s1 = *reinterpret_cast<const float4*>(alphaS + (size_t)s*8 + 4);
    float4 e0 = *reinterpret_cast<const float4*>(alphaE + (size_t)e*8);
    float4 e1 = *reinterpret_cast<const float4*>(alphaE + (size_t)e*8 + 4);
    float sv[8] = {s0.x,s0.y,s0.z,s0.w,s1.x,s1.y,s1.z,s1.w};
    float ev[8] = {e0.x,e0.y,e0.z,e0.w,e1.x,e1.y,e1.z,e1.w};
    float exv[8];
    #pragma unroll
    for (int h=0;h<8;h++){ float t = leaky02(sv[h]+adn[h]+ev[h]); exv[h]=__expf(t-mx[h]); denom[h]+=exv[h]; }
    const float* xs = xp + (size_t)s*HC;
    #pragma unroll
    for (int k=0;k<KR;k++){
      float exk = (HC==512) ? exv[k] : ((lane & 32) ? exv[2*k+1] : exv[2*k]);
      acc[k] = fmaf(exk, xs[lane + 64*k], acc[k]);
    }
  }
  #pragma unroll
  for (int k=0;k<KR;k++){
    float dk = (HC==512) ? denom[k] : ((lane & 32) ? denom[2*k+1] : denom[2*k]);
    float v = acc[k] / (dk + 1e-16f) + bias[lane + 64*k];
    if (apply_elu) v = (v > 0.f) ? v : expm1f(v);
    out[(size_t)n*HC + lane + 64*k] = v;
  }
}

// ---------------- mean pool (batch sorted) + final linear ----------------
__device__ __forceinline__ int lower_bound_i(const int* a, int n, int key){
  int lo=0, hi=n;
  while (lo<hi){ int mid=(lo+hi)>>1; if (a[mid]<key) lo=mid+1; else hi=mid; }
  return lo;
}

__global__ void pool_kernel(const float* __restrict__ h, const int* __restrict__ batch,
                            float* __restrict__ pooled, int N){
  int g = blockIdx.x;
  int c = threadIdx.x; // 256
  int start = lower_bound_i(batch, N, g);
  int end   = lower_bound_i(batch, N, g+1);
  float s = 0.f;
  for (int i=start;i<end;i++) s += h[(size_t)i*256 + c];
  pooled[g*256 + c] = s / fmaxf((float)(end-start), 1.f);
}

__global__ void final_kernel(const float* __restrict__ pooled, const float* __restrict__ Wc,
                             const float* __restrict__ bc, float* __restrict__ out){
  int g = blockIdx.x; int j = threadIdx.x;
  if (j >= 32) return;
  const float* p = pooled + g*256;
  const float* w = Wc + (size_t)j*256;
  float s = 0.f;
  for (int c=0;c<256;c++) s = fmaf(p[c], w[c], s);
  out[g*32 + j] = s + bc[j];
}

extern "C" void kernel_launch(void* const* d_in, const int* in_sizes, int n_in,
                              void* d_out, int out_size, void* d_ws, size_t ws_size,
                              hipStream_t stream){
  (void)n_in; (void)out_size; (void)ws_size;
  const float* x   = (const float*)d_in[0];
  const float* ea  = (const float*)d_in[1];
  const float* Wt[3]  = {(const float*)d_in[2],  (const float*)d_in[8],  (const float*)d_in[14]};
  const float* Wet[3] = {(const float*)d_in[3],  (const float*)d_in[9],  (const float*)d_in[15]};
  const float* ast[3] = {(const float*)d_in[4],  (const float*)d_in[10], (const float*)d_in[16]};
  const float* adt[3] = {(const float*)d_in[5],  (const float*)d_in[11], (const float*)d_in[17]};
  const float* aet[3] = {(const float*)d_in[6],  (const float*)d_in[12], (const float*)d_in[18]};
  const float* bt[3]  = {(const float*)d_in[7],  (const float*)d_in[13], (const float*)d_in[19]};
  const float* Wc  = (const float*)d_in[20];
  const float* bc  = (const float*)d_in[21];
  const int* ei    = (const int*)d_in[22];
  const int* batch = (const int*)d_in[23];
  int N = in_sizes[0] / 64;
  int E = in_sizes[1] / 147;
  const int* srcp = ei;
  const int* dstp = ei + E;

  char* w = (char*)d_ws;
  size_t off = 0;
  auto carve = [&](size_t bytes)->char*{ char* p = w + off; off += (bytes + 255) & ~(size_t)255; return p; };
  float* bufA   = (float*)carve((size_t)N*512*4);
  float* bufB   = (float*)carve((size_t)N*512*4);
  float* alphaE = (float*)carve((size_t)E*8*4);
  float* loopAE = (float*)carve((size_t)N*8*4);
  float* alphaS = (float*)carve((size_t)N*8*4);
  float* alphaD = (float*)carve((size_t)N*8*4);
  float* wfold  = (float*)carve((size_t)147*24*4);
  float* pooled = (float*)carve((size_t)128*256*4);
  int* row_ptr  = (int*)carve((size_t)(N+1)*4);
  int* cnt      = (int*)carve((size_t)N*4);
  int* cursor   = (int*)carve((size_t)N*4);
  int* csr      = (int*)carve((size_t)E*4);

  hipMemsetAsync(cnt,    0, (size_t)N*4, stream);
  hipMemsetAsync(cursor, 0, (size_t)N*4, stream);

  count_kernel  <<<(E+255)/256, 256, 0, stream>>>(dstp, cnt, E);
  scan_kernel   <<<1, 1024, 0, stream>>>(cnt, row_ptr, N);
  scatter_kernel<<<(E+255)/256, 256, 0, stream>>>(dstp, row_ptr, cursor, csr, E);
  wfold_kernel  <<<(147*24+255)/256, 256, 0, stream>>>(Wet[0], aet[0], Wet[1], aet[1], Wet[2], aet[2], wfold);

  const int HCs[3]  = {512, 512, 256};
  const int CINs[3] = {64, 512, 512};
  for (int l=0; l<3; l++){
    int HC = HCs[l], CIN = CINs[l];
    const float* hin = (l==0) ? x : bufB;
    dim3 ggrid((N+63)/64, HC/64);
    gemm_nt_kernel<<<ggrid, 256, 0, stream>>>(hin, Wt[l], bufA, N, HC, CIN);
    int tsd = N*8;
    if (HC==512) alpha_sd_kernel<512><<<(tsd+255)/256, 256, 0, stream>>>(bufA, ast[l], adt[l], alphaS, alphaD, N);
    else         alpha_sd_kernel<256><<<(tsd+255)/256, 256, 0, stream>>>(bufA, ast[l], adt[l], alphaS, alphaD, N);
    edge_alpha_kernel<<<(E+255)/256, 256, 0, stream>>>(ea, wfold, l, alphaE, E);
    loop_alpha_kernel<<<(N*8+255)/256, 256, 0, stream>>>(alphaE, row_ptr, csr, loopAE, N);
    int ablocks = (N + 3) / 4; // 4 waves per block, one node per wave
    if (HC==512) aggregate_kernel<512><<<ablocks, 256, 0, stream>>>(bufA, alphaS, alphaD, alphaE, loopAE, row_ptr, csr, srcp, bt[l], bufB, N, l<2 ? 1 : 0);
    else         aggregate_kernel<256><<<ablocks, 256, 0, stream>>>(bufA, alphaS, alphaD, alphaE, loopAE, row_ptr, csr, srcp, bt[l], bufB, N, l<2 ? 1 : 0);
  }
  pool_kernel <<<128, 256, 0, stream>>>(bufB, batch, pooled, N);
  final_kernel<<<128, 64, 0, stream>>>(pooled, Wc, bc, (float*)d_out);
}

// Round 2
// 1034.416 us; speedup vs baseline: 1.5368x; 1.5368x over previous
//
#include <hip/hip_runtime.h>
#include <hip/hip_bf16.h>
#include <math.h>

typedef __attribute__((ext_vector_type(8))) _Float16 f16x8;
typedef __attribute__((ext_vector_type(4))) float f32x4;

#define AS1(p) ((const __attribute__((address_space(1))) void*)(p))
#define AS3(p) ((__attribute__((address_space(3))) void*)(p))

__device__ __forceinline__ float leaky02(float x){ return x > 0.f ? x : 0.2f*x; }
__device__ __forceinline__ ushort f2h(float f){ _Float16 h = (_Float16)f; return *(ushort*)&h; }
__device__ __forceinline__ float h2f(ushort u){ _Float16 h = *(_Float16*)&u; return (float)h; }

// ---------------- CSR build over dst ----------------
__global__ void count_kernel(const int* __restrict__ dst, int* __restrict__ cnt, int E){
  int e = blockIdx.x*blockDim.x + threadIdx.x;
  if (e < E) atomicAdd(&cnt[dst[e]], 1);
}

__global__ __launch_bounds__(1024) void scan_kernel(const int* __restrict__ cnt, int* __restrict__ row_ptr, int N){
  __shared__ int sd[1024];
  int t = threadIdx.x;
  int chunk = (N + 1023) >> 10;
  int b0 = t*chunk, b1 = min(b0+chunk, N); if (b0 > N) b0 = N;
  int s = 0;
  for (int i=b0;i<b1;i++) s += cnt[i];
  sd[t] = s;
  __syncthreads();
  for (int off=1; off<1024; off<<=1){
    int v = (t>=off)? sd[t-off]:0;
    __syncthreads();
    sd[t]+=v;
    __syncthreads();
  }
  int run = sd[t]-s;
  for (int i=b0;i<b1;i++){ run += cnt[i]; row_ptr[i+1]=run; }
  if (t==0) row_ptr[0]=0;
}

__global__ void scatter_kernel(const int* __restrict__ dst, const int* __restrict__ row_ptr,
                               int* __restrict__ cursor, int* __restrict__ csr, int E){
  int e = blockIdx.x*blockDim.x + threadIdx.x;
  if (e < E){
    int d = dst[e];
    int pos = row_ptr[d] + atomicAdd(&cursor[d], 1);
    csr[pos] = e;
  }
}

// ---------------- fp32 -> fp16 conversion ----------------
__global__ void conv_h_kernel(const float* __restrict__ in, ushort* __restrict__ out, int n4){
  int i = blockIdx.x*256 + threadIdx.x;
  if (i >= n4) return;
  float4 v = reinterpret_cast<const float4*>(in)[i];
  ushort4 o; o.x=f2h(v.x); o.y=f2h(v.y); o.z=f2h(v.z); o.w=f2h(v.w);
  reinterpret_cast<ushort4*>(out)[i] = o;
}

// ---------------- fold We with a_e: wf[d][l*8+h] ----------------
__global__ void wfold_kernel(const float* __restrict__ We0, const float* __restrict__ ae0,
                             const float* __restrict__ We1, const float* __restrict__ ae1,
                             const float* __restrict__ We2, const float* __restrict__ ae2,
                             float* __restrict__ wf){
  int t = blockIdx.x*blockDim.x + threadIdx.x;
  if (t >= 147*24) return;
  int d = t / 24, j = t % 24;
  int l = j >> 3, h = j & 7;
  const float* We = (l==0) ? We0 : (l==1) ? We1 : We2;
  const float* ae = (l==0) ? ae0 : (l==1) ? ae1 : ae2;
  int C = (l==2) ? 32 : 64;
  float s = 0.f;
  for (int c=0;c<C;c++) s = fmaf(We[(size_t)(h*C+c)*147 + d], ae[h*C+c], s);
  wf[t] = s;
}

// ---------------- per-edge edge-term for ALL 3 layers at once: alphaE[e][24] ----------------
__global__ __launch_bounds__(256) void edge_alpha_all_kernel(const float* __restrict__ ea, const float* __restrict__ wf,
                                                             float* __restrict__ alphaE, int E){
  __shared__ float wfl[147*24];
  for (int i=threadIdx.x; i<147*24; i+=256) wfl[i] = wf[i];
  __syncthreads();
  int e = blockIdx.x*256 + threadIdx.x;
  if (e >= E) return;
  const float* row = ea + (size_t)e*147;
  float acc[24];
  #pragma unroll
  for (int j=0;j<24;j++) acc[j] = 0.f;
  for (int d=0; d<147; d++){
    float v = row[d];
    #pragma unroll
    for (int j=0;j<24;j++) acc[j] = fmaf(v, wfl[d*24+j], acc[j]);
  }
  #pragma unroll
  for (int j=0;j<24;j++) alphaE[(size_t)e*24 + j] = acc[j];
}

// ---------------- self-loop edge term (mean of incoming alphaE), all layers ----------------
__global__ __launch_bounds__(192) void loop_alpha_all_kernel(const float* __restrict__ alphaE, const int* __restrict__ row_ptr,
                                                             const int* __restrict__ csr, float* __restrict__ loopAE, int N){
  int n = blockIdx.x*8 + threadIdx.x/24;
  int j = threadIdx.x%24;
  if (n >= N) return;
  int row = row_ptr[n], end = row_ptr[n+1];
  float s = 0.f;
  for (int i=row;i<end;i++) s += alphaE[(size_t)csr[i]*24 + j];
  loopAE[(size_t)n*24 + j] = s / fmaxf((float)(end-row), 1.0f);
}

// ---------------- per-node alpha_s, alpha_d from xp ----------------
template<int HC>
__global__ void alpha_sd_kernel(const float* __restrict__ xp, const float* __restrict__ a_s, const float* __restrict__ a_d,
                                float* __restrict__ alphaS, float* __restrict__ alphaD, int N){
  constexpr int C = HC/8;
  int t = blockIdx.x*blockDim.x + threadIdx.x;
  int n = t >> 3;
  if (n >= N) return;
  int h = t & 7;
  const float* xr = xp + (size_t)n*HC + h*C;
  const float* sr = a_s + h*C;
  const float* dr = a_d + h*C;
  float ss = 0.f, sd = 0.f;
  for (int c=0;c<C;c++){ float v = xr[c]; ss = fmaf(v, sr[c], ss); sd = fmaf(v, dr[c], sd); }
  alphaS[t] = ss; alphaD[t] = sd;
}

// ---------------- fp16-MFMA GEMM: C_f32[M][Nn] = A_h[M][K] * B_h[Nn][K]^T ----------------
// 128x128 tile, BK=64, 4 waves each owning a 64x64 quadrant (4x4 fragments of 16x16x32).
__global__ __launch_bounds__(256) void gemm_mfma_kernel(const ushort* __restrict__ A, const ushort* __restrict__ B,
                                                        float* __restrict__ C, int M, int Nn, int K){
  __shared__ ushort As[128*64];
  __shared__ ushort Bs[128*64];
  int m0 = blockIdx.x*128, n0 = blockIdx.y*128;
  int wave = threadIdx.x >> 6, lane = threadIdx.x & 63;
  int wr = wave >> 1, wc = wave & 1;
  f32x4 acc[4][4];
  #pragma unroll
  for (int m=0;m<4;m++)
    #pragma unroll
    for (int n=0;n<4;n++) acc[m][n] = (f32x4){0.f,0.f,0.f,0.f};

  int lrow = lane >> 3;   // 0..7
  int lcol = lane & 7;    // 16B chunk
  int fr = lane & 15;     // fragment row/col
  int fq = lane >> 4;     // 0..3 (k-group / acc row group)

  for (int k0=0; k0<K; k0+=64){
    #pragma unroll
    for (int q=0;q<4;q++){
      int r = q*32 + wave*8 + lrow;
      int gr = m0 + r; if (gr > M-1) gr = M-1;
      const ushort* gp = A + (size_t)gr*K + k0 + lcol*8;
      __builtin_amdgcn_global_load_lds(AS1(gp), AS3(&As[(q*32 + wave*8)*64]), 16, 0, 0);
    }
    #pragma unroll
    for (int q=0;q<4;q++){
      int r = q*32 + wave*8 + lrow;
      const ushort* gp = B + (size_t)(n0 + r)*K + k0 + lcol*8;
      __builtin_amdgcn_global_load_lds(AS1(gp), AS3(&Bs[(q*32 + wave*8)*64]), 16, 0, 0);
    }
    __syncthreads();
    #pragma unroll
    for (int kk=0; kk<64; kk+=32){
      f16x8 a[4], b[4];
      #pragma unroll
      for (int m=0;m<4;m++) a[m] = *(const f16x8*)&As[(wr*64 + m*16 + fr)*64 + kk + fq*8];
      #pragma unroll
      for (int n=0;n<4;n++) b[n] = *(const f16x8*)&Bs[(wc*64 + n*16 + fr)*64 + kk + fq*8];
      #pragma unroll
      for (int m=0;m<4;m++)
        #pragma unroll
        for (int n=0;n<4;n++)
          acc[m][n] = __builtin_amdgcn_mfma_f32_16x16x32_f16(a[m], b[n], acc[m][n], 0, 0, 0);
    }
    __syncthreads();
  }
  // C/D layout: col = lane&15, row = (lane>>4)*4 + reg
  #pragma unroll
  for (int m=0;m<4;m++){
    #pragma unroll
    for (int j=0;j<4;j++){
      int row = m0 + wr*64 + m*16 + fq*4 + j;
      if (row < M){
        float* cp = C + (size_t)row*Nn + n0 + wc*64 + fr;
        #pragma unroll
        for (int n=0;n<4;n++) cp[n*16] = acc[m][n][j];
      }
    }
  }
}

// ---------------- fused per-dst softmax + weighted aggregate (one wave per node) ----------------
// alphaE/loopAE passed pre-offset by l*8, stride 24.
template<int HC, int WRITE_HALF, int ELU>
__global__ __launch_bounds__(256) void aggregate_kernel(
    const float* __restrict__ xp, const float* __restrict__ alphaS, const float* __restrict__ alphaD,
    const float* __restrict__ alphaE, const float* __restrict__ loopAE,
    const int* __restrict__ row_ptr, const int* __restrict__ csr, const int* __restrict__ src,
    const float* __restrict__ bias, ushort* __restrict__ outh, float* __restrict__ outf, int N){
  constexpr int KR = HC/64;
  int n = blockIdx.x*(blockDim.x>>6) + (threadIdx.x>>6);
  int lane = threadIdx.x & 63;
  if (n >= N) return;
  int row = row_ptr[n], end = row_ptr[n+1];
  float adn[8], ls[8], mx[8];
  {
    float4 a0 = *reinterpret_cast<const float4*>(alphaS + (size_t)n*8);
    float4 a1 = *reinterpret_cast<const float4*>(alphaS + (size_t)n*8 + 4);
    float4 d0 = *reinterpret_cast<const float4*>(alphaD + (size_t)n*8);
    float4 d1 = *reinterpret_cast<const float4*>(alphaD + (size_t)n*8 + 4);
    float4 l0 = *reinterpret_cast<const float4*>(loopAE + (size_t)n*24);
    float4 l1 = *reinterpret_cast<const float4*>(loopAE + (size_t)n*24 + 4);
    float asn[8] = {a0.x,a0.y,a0.z,a0.w,a1.x,a1.y,a1.z,a1.w};
    float tdn[8] = {d0.x,d0.y,d0.z,d0.w,d1.x,d1.y,d1.z,d1.w};
    float la [8] = {l0.x,l0.y,l0.z,l0.w,l1.x,l1.y,l1.z,l1.w};
    #pragma unroll
    for (int h=0;h<8;h++){ adn[h]=tdn[h]; ls[h] = leaky02(asn[h]+adn[h]+la[h]); mx[h]=ls[h]; }
  }
  for (int i=row;i<end;i++){
    int e = csr[i]; int s = src[e];
    float4 s0 = *reinterpret_cast<const float4*>(alphaS + (size_t)s*8);
    float4 s1 = *reinterpret_cast<const float4*>(alphaS + (size_t)s*8 + 4);
    float4 e0 = *reinterpret_cast<const float4*>(alphaE + (size_t)e*24);
    float4 e1 = *reinterpret_cast<const float4*>(alphaE + (size_t)e*24 + 4);
    float sv[8] = {s0.x,s0.y,s0.z,s0.w,s1.x,s1.y,s1.z,s1.w};
    float ev[8] = {e0.x,e0.y,e0.z,e0.w,e1.x,e1.y,e1.z,e1.w};
    #pragma unroll
    for (int h=0;h<8;h++){ float t = leaky02(sv[h]+adn[h]+ev[h]); mx[h]=fmaxf(mx[h],t); }
  }
  float denom[8], exs[8], acc[KR];
  #pragma unroll
  for (int h=0;h<8;h++){ exs[h] = __expf(ls[h]-mx[h]); denom[h]=exs[h]; }
  const float* xn = xp + (size_t)n*HC;
  #pragma unroll
  for (int k=0;k<KR;k++){
    float exk = (HC==512) ? exs[k] : ((lane & 32) ? exs[2*k+1] : exs[2*k]);
    acc[k] = exk * xn[lane + 64*k];
  }
  for (int i=row;i<end;i++){
    int e = csr[i]; int s = src[e];
    float4 s0 = *reinterpret_cast<const float4*>(alphaS + (size_t)s*8);
    float4 s1 = *reinterpret_cast<const float4*>(alphaS + (size_t)s*8 + 4);
    float4 e0 = *reinterpret_cast<const float4*>(alphaE + (size_t)e*24);
    float4 e1 = *reinterpret_cast<const float4*>(alphaE + (size_t)e*24 + 4);
    float sv[8] = {s0.x,s0.y,s0.z,s0.w,s1.x,s1.y,s1.z,s1.w};
    float ev[8] = {e0.x,e0.y,e0.z,e0.w,e1.x,e1.y,e1.z,e1.w};
    float exv[8];
    #pragma unroll
    for (int h=0;h<8;h++){ float t = leaky02(sv[h]+adn[h]+ev[h]); exv[h]=__expf(t-mx[h]); denom[h]+=exv[h]; }
    const float* xs = xp + (size_t)s*HC;
    #pragma unroll
    for (int k=0;k<KR;k++){
      float exk = (HC==512) ? exv[k] : ((lane & 32) ? exv[2*k+1] : exv[2*k]);
      acc[k] = fmaf(exk, xs[lane + 64*k], acc[k]);
    }
  }
  #pragma unroll
  for (int k=0;k<KR;k++){
    float dk = (HC==512) ? denom[k] : ((lane & 32) ? denom[2*k+1] : denom[2*k]);
    float v = acc[k] / (dk + 1e-16f) + bias[lane + 64*k];
    if (ELU) v = (v > 0.f) ? v : expm1f(v);
    if (WRITE_HALF) outh[(size_t)n*HC + lane + 64*k] = f2h(v);
    else            outf[(size_t)n*HC + lane + 64*k] = v;
  }
}

// ---------------- mean pool (batch sorted, fp16 h) + final linear ----------------
__device__ __forceinline__ int lower_bound_i(const int* a, int n, int key){
  int lo=0, hi=n;
  while (lo<hi){ int mid=(lo+hi)>>1; if (a[mid]<key) lo=mid+1; else hi=mid; }
  return lo;
}

__global__ void pool_kernel(const ushort* __restrict__ h, const int* __restrict__ batch,
                            float* __restrict__ pooled, int N){
  int g = blockIdx.x;
  int c = threadIdx.x; // 256
  int start = lower_bound_i(batch, N, g);
  int end   = lower_bound_i(batch, N, g+1);
  float s = 0.f;
  for (int i=start;i<end;i++) s += h2f(h[(size_t)i*256 + c]);
  pooled[g*256 + c] = s / fmaxf((float)(end-start), 1.f);
}

__global__ void final_kernel(const float* __restrict__ pooled, const float* __restrict__ Wc,
                             const float* __restrict__ bc, float* __restrict__ out){
  int g = blockIdx.x; int j = threadIdx.x;
  if (j >= 32) return;
  const float* p = pooled + g*256;
  const float* w = Wc + (size_t)j*256;
  float s = 0.f;
  for (int c=0;c<256;c++) s = fmaf(p[c], w[c], s);
  out[g*32 + j] = s + bc[j];
}

extern "C" void kernel_launch(void* const* d_in, const int* in_sizes, int n_in,
                              void* d_out, int out_size, void* d_ws, size_t ws_size,
                              hipStream_t stream){
  (void)n_in; (void)out_size; (void)ws_size;
  const float* x   = (const float*)d_in[0];
  const float* ea  = (const float*)d_in[1];
  const float* Wt[3]  = {(const float*)d_in[2],  (const float*)d_in[8],  (const float*)d_in[14]};
  const float* Wet[3] = {(const float*)d_in[3],  (const float*)d_in[9],  (const float*)d_in[15]};
  const float* ast[3] = {(const float*)d_in[4],  (const float*)d_in[10], (const float*)d_in[16]};
  const float* adt[3] = {(const float*)d_in[5],  (const float*)d_in[11], (const float*)d_in[17]};
  const float* aet[3] = {(const float*)d_in[6],  (const float*)d_in[12], (const float*)d_in[18]};
  const float* bt[3]  = {(const float*)d_in[7],  (const float*)d_in[13], (const float*)d_in[19]};
  const float* Wc  = (const float*)d_in[20];
  const float* bc  = (const float*)d_in[21];
  const int* ei    = (const int*)d_in[22];
  const int* batch = (const int*)d_in[23];
  int N = in_sizes[0] / 64;
  int E = in_sizes[1] / 147;
  const int* srcp = ei;
  const int* dstp = ei + E;

  char* w = (char*)d_ws;
  size_t off = 0;
  auto carve = [&](size_t bytes)->char*{ char* p = w + off; off += (bytes + 255) & ~(size_t)255; return p; };
  float*  bufA   = (float*) carve((size_t)N*512*4);   // xp fp32 (GEMM out)
  ushort* hb     = (ushort*)carve((size_t)N*512*2);   // h fp16 (layer inputs / final h)
  ushort* xb     = (ushort*)carve((size_t)N*64*2);
  ushort* Wb[3];
  Wb[0] = (ushort*)carve((size_t)512*64*2);
  Wb[1] = (ushort*)carve((size_t)512*512*2);
  Wb[2] = (ushort*)carve((size_t)256*512*2);
  float*  alphaE = (float*) carve((size_t)E*24*4);
  float*  loopAE = (float*) carve((size_t)N*24*4);
  float*  alphaS = (float*) carve((size_t)N*8*4);
  float*  alphaD = (float*) carve((size_t)N*8*4);
  float*  wfold  = (float*) carve((size_t)147*24*4);
  float*  pooled = (float*) carve((size_t)128*256*4);
  int* row_ptr   = (int*)   carve((size_t)(N+1)*4);
  int* cnt       = (int*)   carve((size_t)N*4);
  int* cursor    = (int*)   carve((size_t)N*4);
  int* csr       = (int*)   carve((size_t)E*4);

  hipMemsetAsync(cnt,    0, (size_t)N*4, stream);
  hipMemsetAsync(cursor, 0, (size_t)N*4, stream);

  count_kernel  <<<(E+255)/256, 256, 0, stream>>>(dstp, cnt, E);
  scan_kernel   <<<1, 1024, 0, stream>>>(cnt, row_ptr, N);
  scatter_kernel<<<(E+255)/256, 256, 0, stream>>>(dstp, row_ptr, cursor, csr, E);
  wfold_kernel  <<<(147*24+255)/256, 256, 0, stream>>>(Wet[0], aet[0], Wet[1], aet[1], Wet[2], aet[2], wfold);

  conv_h_kernel<<<(N*64/4+255)/256, 256, 0, stream>>>(x, xb, N*64/4);
  conv_h_kernel<<<(512*64/4+255)/256, 256, 0, stream>>>(Wt[0], Wb[0], 512*64/4);
  conv_h_kernel<<<(512*512/4+255)/256, 256, 0, stream>>>(Wt[1], Wb[1], 512*512/4);
  conv_h_kernel<<<(256*512/4+255)/256, 256, 0, stream>>>(Wt[2], Wb[2], 256*512/4);

  edge_alpha_all_kernel<<<(E+255)/256, 256, 0, stream>>>(ea, wfold, alphaE, E);
  loop_alpha_all_kernel<<<(N+7)/8, 192, 0, stream>>>(alphaE, row_ptr, csr, loopAE, N);

  const int HCs[3]  = {512, 512, 256};
  const int CINs[3] = {64, 512, 512};
  for (int l=0; l<3; l++){
    int HC = HCs[l], CIN = CINs[l];
    const ushort* Ain = (l==0) ? xb : hb;
    dim3 ggrid((N+127)/128, HC/128);
    gemm_mfma_kernel<<<ggrid, 256, 0, stream>>>(Ain, Wb[l], bufA, N, HC, CIN);
    int tsd = N*8;
    if (HC==512) alpha_sd_kernel<512><<<(tsd+255)/256, 256, 0, stream>>>(bufA, ast[l], adt[l], alphaS, alphaD, N);
    else         alpha_sd_kernel<256><<<(tsd+255)/256, 256, 0, stream>>>(bufA, ast[l], adt[l], alphaS, alphaD, N);
    int ablocks = (N + 3) / 4; // 4 waves per block, one node per wave
    if (l==0)
      aggregate_kernel<512,1,1><<<ablocks, 256, 0, stream>>>(bufA, alphaS, alphaD, alphaE + 0*8, loopAE + 0*8, row_ptr, csr, srcp, bt[l], hb, nullptr, N);
    else if (l==1)
      aggregate_kernel<512,1,1><<<ablocks, 256, 0, stream>>>(bufA, alphaS, alphaD, alphaE + 1*8, loopAE + 1*8, row_ptr, csr, srcp, bt[l], hb, nullptr, N);
    else
      aggregate_kernel<256,1,0><<<ablocks, 256, 0, stream>>>(bufA, alphaS, alphaD, alphaE + 2*8, loopAE + 2*8, row_ptr, csr, srcp, bt[l], hb, nullptr, N);
  }
  pool_kernel <<<128, 256, 0, stream>>>(hb, batch, pooled, N);
  final_kernel<<<128, 64, 0, stream>>>(pooled, Wc, bc, (float*)d_out);
}

// Round 3
// 728.561 us; speedup vs baseline: 2.1820x; 1.4198x over previous
//
#include <hip/hip_runtime.h>
#include <hip/hip_bf16.h>
#include <math.h>

typedef __attribute__((ext_vector_type(8))) _Float16 f16x8;
typedef __attribute__((ext_vector_type(4))) _Float16 f16x4;
typedef __attribute__((ext_vector_type(4))) float f32x4;

#define AS1(p) ((const __attribute__((address_space(1))) void*)(p))
#define AS3(p) ((__attribute__((address_space(3))) void*)(p))

__device__ __forceinline__ float leaky02(float x){ return x > 0.f ? x : 0.2f*x; }
__device__ __forceinline__ ushort f2h(float f){ _Float16 h = (_Float16)f; return *(ushort*)&h; }
__device__ __forceinline__ float h2f(ushort u){ _Float16 h = *(_Float16*)&u; return (float)h; }

// ---------------- CSR build over dst ----------------
__global__ void count_kernel(const int* __restrict__ dst, int* __restrict__ cnt, int E){
  int e = blockIdx.x*blockDim.x + threadIdx.x;
  if (e < E) atomicAdd(&cnt[dst[e]], 1);
}

__global__ __launch_bounds__(1024) void scan_kernel(const int* __restrict__ cnt, int* __restrict__ row_ptr, int N){
  __shared__ int sd[1024];
  int t = threadIdx.x;
  int chunk = (N + 1023) >> 10;
  int b0 = t*chunk; if (b0 > N) b0 = N;
  int b1 = min(b0+chunk, N);
  int s = 0;
  for (int i=b0;i<b1;i++) s += cnt[i];
  sd[t] = s;
  __syncthreads();
  for (int off=1; off<1024; off<<=1){
    int v = (t>=off)? sd[t-off]:0;
    __syncthreads();
    sd[t]+=v;
    __syncthreads();
  }
  int run = sd[t]-s;
  for (int i=b0;i<b1;i++){ run += cnt[i]; row_ptr[i+1]=run; }
  if (t==0) row_ptr[0]=0;
}

__global__ void scatter_kernel(const int* __restrict__ dst, const int* __restrict__ row_ptr,
                               int* __restrict__ cursor, int* __restrict__ csr, int E){
  int e = blockIdx.x*blockDim.x + threadIdx.x;
  if (e < E){
    int d = dst[e];
    int pos = row_ptr[d] + atomicAdd(&cursor[d], 1);
    csr[pos] = e;
  }
}

// ---------------- fp32 -> fp16 conversion (flat) ----------------
__global__ void conv_h_kernel(const float* __restrict__ in, ushort* __restrict__ out, int n4){
  int i = blockIdx.x*256 + threadIdx.x;
  if (i >= n4) return;
  float4 v = reinterpret_cast<const float4*>(in)[i];
  ushort4 o; o.x=f2h(v.x); o.y=f2h(v.y); o.z=f2h(v.z); o.w=f2h(v.w);
  reinterpret_cast<ushort4*>(out)[i] = o;
}

// ---------------- ea fp32 [E][147] -> fp16 padded [E][160] ----------------
__global__ void conv_ea_kernel(const float* __restrict__ ea, ushort* __restrict__ eah, int E){
  int o = blockIdx.x*256 + threadIdx.x;  // output ushort2 index
  int total = E*80;
  if (o >= total) return;
  int e = o/80, p = o%80;
  int d = 2*p;
  float v0 = (d   < 147) ? ea[(size_t)e*147 + d]   : 0.f;
  float v1 = (d+1 < 147) ? ea[(size_t)e*147 + d+1] : 0.f;
  ushort2 u; u.x = f2h(v0); u.y = f2h(v1);
  reinterpret_cast<ushort2*>(eah)[o] = u;
}

// ---------------- fold We with a_e: wf[d][l*8+h] ----------------
__global__ void wfold_kernel(const float* __restrict__ We0, const float* __restrict__ ae0,
                             const float* __restrict__ We1, const float* __restrict__ ae1,
                             const float* __restrict__ We2, const float* __restrict__ ae2,
                             float* __restrict__ wf){
  int t = blockIdx.x*blockDim.x + threadIdx.x;
  if (t >= 147*24) return;
  int d = t / 24, j = t % 24;
  int l = j >> 3, h = j & 7;
  const float* We = (l==0) ? We0 : (l==1) ? We1 : We2;
  const float* ae = (l==0) ? ae0 : (l==1) ? ae1 : ae2;
  int C = (l==2) ? 32 : 64;
  float s = 0.f;
  for (int c=0;c<C;c++) s = fmaf(We[(size_t)(h*C+c)*147 + d], ae[h*C+c], s);
  wf[t] = s;
}

// wfold fp32 [147][24] -> fp16 B matrix [32][160] (K-major, zero padded)
__global__ void wfoldh_kernel(const float* __restrict__ wf, ushort* __restrict__ Bh){
  int t = blockIdx.x*256 + threadIdx.x;
  if (t >= 32*160) return;
  int j = t/160, d = t%160;
  float v = (j<24 && d<147) ? wf[d*24+j] : 0.f;
  Bh[t] = f2h(v);
}

// ---------------- alphaE[E][24] = eah[E][160] @ Bh[32][160]^T via MFMA ----------------
__global__ __launch_bounds__(256) void edge_alpha_mfma_kernel(const ushort* __restrict__ eah, const ushort* __restrict__ Bh,
                                                              float* __restrict__ alphaE, int E){
  int wave = threadIdx.x>>6, lane = threadIdx.x&63;
  int fr = lane&15, fq = lane>>4;
  int m0 = blockIdx.x*64 + wave*16;
  f32x4 acc0 = {0.f,0.f,0.f,0.f}, acc1 = {0.f,0.f,0.f,0.f};
  int row = m0 + fr; if (row > E-1) row = E-1;
  const ushort* ar = eah + (size_t)row*160 + fq*8;
  const ushort* b0 = Bh + (size_t)fr*160      + fq*8;
  const ushort* b1 = Bh + (size_t)(16+fr)*160 + fq*8;
  #pragma unroll
  for (int k=0;k<160;k+=32){
    f16x8 a = *(const f16x8*)(ar + k);
    f16x8 p = *(const f16x8*)(b0 + k);
    f16x8 q = *(const f16x8*)(b1 + k);
    acc0 = __builtin_amdgcn_mfma_f32_16x16x32_f16(a, p, acc0, 0, 0, 0);
    acc1 = __builtin_amdgcn_mfma_f32_16x16x32_f16(a, q, acc1, 0, 0, 0);
  }
  #pragma unroll
  for (int j=0;j<4;j++){
    int r = m0 + fq*4 + j;
    if (r < E){
      alphaE[(size_t)r*24 + fr] = acc0[j];
      if (fr < 8) alphaE[(size_t)r*24 + 16 + fr] = acc1[j];
    }
  }
}

// ---------------- self-loop edge term (mean of incoming alphaE), all layers ----------------
__global__ __launch_bounds__(192) void loop_alpha_all_kernel(const float* __restrict__ alphaE, const int* __restrict__ row_ptr,
                                                             const int* __restrict__ csr, float* __restrict__ loopAE, int N){
  int n = blockIdx.x*8 + threadIdx.x/24;
  int j = threadIdx.x%24;
  if (n >= N) return;
  int row = row_ptr[n], end = row_ptr[n+1];
  float s = 0.f;
  for (int i=row;i<end;i++) s += alphaE[(size_t)csr[i]*24 + j];
  loopAE[(size_t)n*24 + j] = s / fmaxf((float)(end-row), 1.0f);
}

// ---------------- per-node alpha_s, alpha_d from fp16 xh ----------------
template<int HC>
__global__ void alpha_sd_kernel(const ushort* __restrict__ xh, const float* __restrict__ a_s, const float* __restrict__ a_d,
                                float* __restrict__ alphaS, float* __restrict__ alphaD, int N){
  constexpr int C = HC/8;
  int t = blockIdx.x*blockDim.x + threadIdx.x;
  int n = t >> 3;
  if (n >= N) return;
  int h = t & 7;
  const ushort* xr = xh + (size_t)n*HC + h*C;
  const float* sr = a_s + h*C;
  const float* dr = a_d + h*C;
  float ss = 0.f, sd = 0.f;
  for (int c=0;c<C;c+=8){
    f16x8 v = *(const f16x8*)(xr + c);
    #pragma unroll
    for (int u=0;u<8;u++){ float f = (float)v[u]; ss = fmaf(f, sr[c+u], ss); sd = fmaf(f, dr[c+u], sd); }
  }
  alphaS[t] = ss; alphaD[t] = sd;
}

// ---------------- fp16-MFMA GEMM: C_h[M][Nn] = A_h[M][K] * B_h[Nn][K]^T, XOR-swizzled LDS ----------------
__global__ __launch_bounds__(256) void gemm_mfma_kernel(const ushort* __restrict__ A, const ushort* __restrict__ B,
                                                        ushort* __restrict__ C, int M, int Nn, int K){
  __shared__ ushort As[128*64];
  __shared__ ushort Bs[128*64];
  int m0 = blockIdx.x*128, n0 = blockIdx.y*128;
  int wave = threadIdx.x >> 6, lane = threadIdx.x & 63;
  int wr = wave >> 1, wc = wave & 1;
  f32x4 acc[4][4];
  #pragma unroll
  for (int m=0;m<4;m++)
    #pragma unroll
    for (int n=0;n<4;n++) acc[m][n] = (f32x4){0.f,0.f,0.f,0.f};

  int lrow = lane >> 3;           // row within 8-row group
  int lcol = lane & 7;            // 16B chunk
  int srcChunk = lcol ^ lrow;     // inverse-swizzled global source (T2 via rule #21)
  int fr = lane & 15;
  int fq = lane >> 4;

  for (int k0=0; k0<K; k0+=64){
    #pragma unroll
    for (int q=0;q<4;q++){
      int r = q*32 + wave*8 + lrow;
      int gr = m0 + r; if (gr > M-1) gr = M-1;
      __builtin_amdgcn_global_load_lds(AS1(A + (size_t)gr*K + k0 + srcChunk*8), AS3(&As[(q*32 + wave*8)*64]), 16, 0, 0);
      __builtin_amdgcn_global_load_lds(AS1(B + (size_t)(n0 + r)*K + k0 + srcChunk*8), AS3(&Bs[(q*32 + wave*8)*64]), 16, 0, 0);
    }
    __syncthreads();
    #pragma unroll
    for (int kk=0; kk<64; kk+=32){
      f16x8 a[4], b[4];
      #pragma unroll
      for (int m=0;m<4;m++){
        int Ra = wr*64 + m*16 + fr;
        int ch = ((kk>>3) + fq) ^ (Ra & 7);
        a[m] = *(const f16x8*)&As[Ra*64 + ch*8];
      }
      #pragma unroll
      for (int n=0;n<4;n++){
        int Rb = wc*64 + n*16 + fr;
        int ch = ((kk>>3) + fq) ^ (Rb & 7);
        b[n] = *(const f16x8*)&Bs[Rb*64 + ch*8];
      }
      #pragma unroll
      for (int m=0;m<4;m++)
        #pragma unroll
        for (int n=0;n<4;n++)
          acc[m][n] = __builtin_amdgcn_mfma_f32_16x16x32_f16(a[m], b[n], acc[m][n], 0, 0, 0);
    }
    __syncthreads();
  }
  #pragma unroll
  for (int m=0;m<4;m++){
    #pragma unroll
    for (int j=0;j<4;j++){
      int row = m0 + wr*64 + m*16 + fq*4 + j;
      if (row < M){
        ushort* cp = C + (size_t)row*Nn + n0 + wc*64 + fr;
        #pragma unroll
        for (int n=0;n<4;n++) cp[n*16] = f2h(acc[m][n][j]);
      }
    }
  }
}

// ---------------- single-pass max-free softmax + aggregate; lane owns V consecutive cols ----------------
template<int HC, int ELU>
__global__ __launch_bounds__(256) void aggregate_kernel(
    const ushort* __restrict__ xh, const float* __restrict__ alphaS, const float* __restrict__ alphaD,
    const float* __restrict__ alphaE, const float* __restrict__ loopAE,
    const int* __restrict__ row_ptr, const int* __restrict__ csr, const int* __restrict__ src,
    const float* __restrict__ bias, ushort* __restrict__ out, int N){
  constexpr int V = HC/64;    // 8 (HC=512) or 4 (HC=256) cols per lane; head = lane>>3 either way
  int n = blockIdx.x*4 + (threadIdx.x>>6);
  if (n >= N) return;
  int lane = threadIdx.x & 63;
  int h = lane >> 3;
  float adn = alphaD[(size_t)n*8 + h];
  float ls = leaky02(alphaS[(size_t)n*8 + h] + adn + loopAE[(size_t)n*24 + h]);
  float ex = __expf(ls);      // max-free: logits are O(10), fp32 exp safe
  float denom = ex;
  float acc[V];
  {
    const ushort* xr = xh + (size_t)n*HC + V*lane;
    if (V == 8){
      f16x8 v = *(const f16x8*)xr;
      #pragma unroll
      for (int j=0;j<8;j++) acc[j] = ex * (float)v[j];
    } else {
      f16x4 v = *(const f16x4*)xr;
      #pragma unroll
      for (int j=0;j<V;j++) acc[j] = ex * (float)v[j];
    }
  }
  int i1 = row_ptr[n+1];
  for (int i=row_ptr[n]; i<i1; i++){
    int e = csr[i]; int s = src[e];
    float t = leaky02(alphaS[(size_t)s*8 + h] + adn + alphaE[(size_t)e*24 + h]);
    float exv = __expf(t);
    denom += exv;
    const ushort* xs = xh + (size_t)s*HC + V*lane;
    if (V == 8){
      f16x8 v = *(const f16x8*)xs;
      #pragma unroll
      for (int j=0;j<8;j++) acc[j] = fmaf(exv, (float)v[j], acc[j]);
    } else {
      f16x4 v = *(const f16x4*)xs;
      #pragma unroll
      for (int j=0;j<V;j++) acc[j] = fmaf(exv, (float)v[j], acc[j]);
    }
  }
  float inv = 1.f/(denom + 1e-16f);
  if (V == 8){
    f16x8 ov;
    #pragma unroll
    for (int j=0;j<8;j++){
      float o = acc[j]*inv + bias[V*lane + j];
      if (ELU) o = (o > 0.f) ? o : expm1f(o);
      ov[j] = (_Float16)o;
    }
    *(f16x8*)(out + (size_t)n*HC + V*lane) = ov;
  } else {
    f16x4 ov;
    #pragma unroll
    for (int j=0;j<V;j++){
      float o = acc[j]*inv + bias[V*lane + j];
      if (ELU) o = (o > 0.f) ? o : expm1f(o);
      ov[j] = (_Float16)o;
    }
    *(f16x4*)(out + (size_t)n*HC + V*lane) = ov;
  }
}

// ---------------- mean pool (batch sorted, fp16 h) + final linear ----------------
__device__ __forceinline__ int lower_bound_i(const int* a, int n, int key){
  int lo=0, hi=n;
  while (lo<hi){ int mid=(lo+hi)>>1; if (a[mid]<key) lo=mid+1; else hi=mid; }
  return lo;
}

__global__ void pool_kernel(const ushort* __restrict__ h, const int* __restrict__ batch,
                            float* __restrict__ pooled, int N){
  int g = blockIdx.x;
  int c = threadIdx.x; // 256
  int start = lower_bound_i(batch, N, g);
  int end   = lower_bound_i(batch, N, g+1);
  float s = 0.f;
  for (int i=start;i<end;i++) s += h2f(h[(size_t)i*256 + c]);
  pooled[g*256 + c] = s / fmaxf((float)(end-start), 1.f);
}

__global__ void final_kernel(const float* __restrict__ pooled, const float* __restrict__ Wc,
                             const float* __restrict__ bc, float* __restrict__ out){
  int g = blockIdx.x; int j = threadIdx.x;
  if (j >= 32) return;
  const float* p = pooled + g*256;
  const float* w = Wc + (size_t)j*256;
  float s = 0.f;
  for (int c=0;c<256;c++) s = fmaf(p[c], w[c], s);
  out[g*32 + j] = s + bc[j];
}

extern "C" void kernel_launch(void* const* d_in, const int* in_sizes, int n_in,
                              void* d_out, int out_size, void* d_ws, size_t ws_size,
                              hipStream_t stream){
  (void)n_in; (void)out_size; (void)ws_size;
  const float* x   = (const float*)d_in[0];
  const float* ea  = (const float*)d_in[1];
  const float* Wt[3]  = {(const float*)d_in[2],  (const float*)d_in[8],  (const float*)d_in[14]};
  const float* Wet[3] = {(const float*)d_in[3],  (const float*)d_in[9],  (const float*)d_in[15]};
  const float* ast[3] = {(const float*)d_in[4],  (const float*)d_in[10], (const float*)d_in[16]};
  const float* adt[3] = {(const float*)d_in[5],  (const float*)d_in[11], (const float*)d_in[17]};
  const float* aet[3] = {(const float*)d_in[6],  (const float*)d_in[12], (const float*)d_in[18]};
  const float* bt[3]  = {(const float*)d_in[7],  (const float*)d_in[13], (const float*)d_in[19]};
  const float* Wc  = (const float*)d_in[20];
  const float* bc  = (const float*)d_in[21];
  const int* ei    = (const int*)d_in[22];
  const int* batch = (const int*)d_in[23];
  int N = in_sizes[0] / 64;
  int E = in_sizes[1] / 147;
  const int* srcp = ei;
  const int* dstp = ei + E;

  char* w = (char*)d_ws;
  size_t off = 0;
  auto carve = [&](size_t bytes)->char*{ char* p = w + off; off += (bytes + 255) & ~(size_t)255; return p; };
  ushort* xh     = (ushort*)carve((size_t)N*512*2);   // GEMM output (fp16)
  ushort* hb     = (ushort*)carve((size_t)N*512*2);   // aggregate output (fp16)
  ushort* xb     = (ushort*)carve((size_t)N*64*2);
  ushort* Wb[3];
  Wb[0] = (ushort*)carve((size_t)512*64*2);
  Wb[1] = (ushort*)carve((size_t)512*512*2);
  Wb[2] = (ushort*)carve((size_t)256*512*2);
  ushort* eah    = (ushort*)carve((size_t)E*160*2);
  ushort* wfBh   = (ushort*)carve((size_t)32*160*2);
  float*  alphaE = (float*) carve((size_t)E*24*4);
  float*  loopAE = (float*) carve((size_t)N*24*4);
  float*  alphaS = (float*) carve((size_t)N*8*4);
  float*  alphaD = (float*) carve((size_t)N*8*4);
  float*  wfold  = (float*) carve((size_t)147*24*4);
  float*  pooled = (float*) carve((size_t)128*256*4);
  int* row_ptr   = (int*)   carve((size_t)(N+1)*4);
  int* cnt       = (int*)   carve((size_t)N*4);
  int* cursor    = (int*)   carve((size_t)N*4);
  int* csr       = (int*)   carve((size_t)E*4);

  hipMemsetAsync(cnt,    0, (size_t)N*4, stream);
  hipMemsetAsync(cursor, 0, (size_t)N*4, stream);

  count_kernel  <<<(E+255)/256, 256, 0, stream>>>(dstp, cnt, E);
  scan_kernel   <<<1, 1024, 0, stream>>>(cnt, row_ptr, N);
  scatter_kernel<<<(E+255)/256, 256, 0, stream>>>(dstp, row_ptr, cursor, csr, E);

  wfold_kernel  <<<(147*24+255)/256, 256, 0, stream>>>(Wet[0], aet[0], Wet[1], aet[1], Wet[2], aet[2], wfold);
  wfoldh_kernel <<<(32*160+255)/256, 256, 0, stream>>>(wfold, wfBh);

  conv_h_kernel<<<(N*64/4+255)/256, 256, 0, stream>>>(x, xb, N*64/4);
  conv_h_kernel<<<(512*64/4+255)/256, 256, 0, stream>>>(Wt[0], Wb[0], 512*64/4);
  conv_h_kernel<<<(512*512/4+255)/256, 256, 0, stream>>>(Wt[1], Wb[1], 512*512/4);
  conv_h_kernel<<<(256*512/4+255)/256, 256, 0, stream>>>(Wt[2], Wb[2], 256*512/4);
  conv_ea_kernel<<<(E*80+255)/256, 256, 0, stream>>>(ea, eah, E);

  edge_alpha_mfma_kernel<<<E/64 + (E%64?1:0), 256, 0, stream>>>(eah, wfBh, alphaE, E);
  loop_alpha_all_kernel <<<(N+7)/8, 192, 0, stream>>>(alphaE, row_ptr, csr, loopAE, N);

  const int HCs[3]  = {512, 512, 256};
  const int CINs[3] = {64, 512, 512};
  for (int l=0; l<3; l++){
    int HC = HCs[l], CIN = CINs[l];
    const ushort* Ain = (l==0) ? xb : hb;
    dim3 ggrid((N+127)/128, HC/128);
    gemm_mfma_kernel<<<ggrid, 256, 0, stream>>>(Ain, Wb[l], xh, N, HC, CIN);
    int tsd = N*8;
    if (HC==512) alpha_sd_kernel<512><<<(tsd+255)/256, 256, 0, stream>>>(xh, ast[l], adt[l], alphaS, alphaD, N);
    else         alpha_sd_kernel<256><<<(tsd+255)/256, 256, 0, stream>>>(xh, ast[l], adt[l], alphaS, alphaD, N);
    int ablocks = (N + 3) / 4;
    if (l==0)
      aggregate_kernel<512,1><<<ablocks, 256, 0, stream>>>(xh, alphaS, alphaD, alphaE + 0*8, loopAE + 0*8, row_ptr, csr, srcp, bt[l], hb, N);
    else if (l==1)
      aggregate_kernel<512,1><<<ablocks, 256, 0, stream>>>(xh, alphaS, alphaD, alphaE + 1*8, loopAE + 1*8, row_ptr, csr, srcp, bt[l], hb, N);
    else
      aggregate_kernel<256,0><<<ablocks, 256, 0, stream>>>(xh, alphaS, alphaD, alphaE + 2*8, loopAE + 2*8, row_ptr, csr, srcp, bt[l], hb, N);
  }
  pool_kernel <<<128, 256, 0, stream>>>(hb, batch, pooled, N);
  final_kernel<<<128, 64, 0, stream>>>(pooled, Wc, bc, (float*)d_out);
}